// Round 8
// baseline (109.182 us; speedup 1.0000x reference)
//
#include <hip/hip_runtime.h>
#include <math.h>

// MarginDevianceLoss: N=4096, D=256, K=8, targets = i/8.
// Outputs: [loss, prec, pos_d, neg_d] fp32.
//
// R22: budget model that fits R16-R21: dur = ~41us workspace re-poison fill
// (timed, untouchable) + kernels + ~3-5us/dispatch. Stats GEMM (~12us) is
// the biggest removable kernel. Recombine ONLY verified pieces, keeping
// dispatch count at 4 (R17-R19 lost to +dispatch overhead, not math):
//   D1 convert+gram fused  (R20-verbatim: passed, fast; plain-store
//      z-partials gPart4[4][65536] + sColP[4][256], no atomics)
//   D2 rowstats            (R20-verbatim, 512 thr: Y=Xb@(Ghi+Glo), classSim,
//      inter/thresh/posLoss once per row)
//   D3 loss GEMM           (R19-verbatim: R16 single-jt loop + slim 2-load
//      prologue; R21's dual-tile epochs REVERTED - null/negative)
//   D4 finalAB             (R16-verbatim)
// Kept lessons: frag-major bf16 Xf + glds B-staging (R11); no inline fp32
// staging (R12); no big atomic fan-in / grid barriers (R7/R13); no reduction
// tails inside register-critical MFMA kernels (R20 spill); dispatch count
// is a first-order cost (R17-R19 vs R16).

#define NROWS 4096
#define DIM   256
#define KCLS  8
#define NJB   32     // j-blocks = partials per row (loss gemm)
#define NT    4      // i-tiles per wave (loss gemm)
#define NZ    4      // gram z-partial copies

typedef __bf16 bf16x8 __attribute__((ext_vector_type(8)));
typedef float  f32x4  __attribute__((ext_vector_type(4)));

// log(1+exp(z)) = max(z,0) + ln2 * log2(1 + exp2(-|z|*log2e));
// log2(1+u), u in (0,1], quartic fit (abs err <= ~4e-4).
__device__ __forceinline__ float softplus_poly(float z) {
    float u = __builtin_exp2f(-1.4426950408889634f * __builtin_fabsf(z));
    float p = u * (1.4426950f + u * (-0.6949650f + u * (0.3454302f + u * -0.0931600f)));
    return fmaf(p, 0.6931471805599453f, fmaxf(z, 0.f));
}

__device__ __forceinline__ unsigned int pack_bf2(float a, float b) {
    unsigned int ua = __float_as_uint(a);
    unsigned int ub = __float_as_uint(b);
    ua = (ua + 0x7FFFu + ((ua >> 16) & 1u)) >> 16;   // RNE
    ub = (ub + 0x7FFFu + ((ub >> 16) & 1u)) >> 16;
    return ua | (ub << 16);
}

// fp32 v -> (hi bf16, lo bf16), hi = RNE(v), lo = RNE(v - hi).
__device__ __forceinline__ void split_pair(float a, float b,
                                           unsigned int& hw, unsigned int& lw) {
    unsigned int ua = __float_as_uint(a), ub = __float_as_uint(b);
    unsigned int ha = (ua + 0x7FFFu + ((ua >> 16) & 1u)) & 0xFFFF0000u;
    unsigned int hb = (ub + 0x7FFFu + ((ub >> 16) & 1u)) & 0xFFFF0000u;
    hw = (ha >> 16) | hb;
    lw = pack_bf2(a - __uint_as_float(ha), b - __uint_as_float(hb));
}

__device__ __forceinline__ void glds16(const unsigned short* g, unsigned short* l) {
    __builtin_amdgcn_global_load_lds(
        (const __attribute__((address_space(1))) void*)g,
        (__attribute__((address_space(3))) void*)l, 16, 0, 0);
}

// ---------------- D1: convert + gram (fused, independent phases) ----------
// convert: Xf[((tile*8+kf)*64+lane)*8+e] = X[tile*16+(lane&15)][kf*32+(lane>>4)*8+e]
// gram (blocks 0..255): gx=b&7, gy=(b>>3)&7, gz=b>>6; 32x32 G tile x 1024-row
// K-chunk; 4 waves split chunk (256 rows each), LDS-reduce, PLAIN float4
// store to gPart4[gz] (each cell written exactly once -> race-free without
// zeroing). gy==0 blocks also emit per-z colsum partials sColP[gz][256].
// Also zeroes the finalAB done-counter.
__global__ __launch_bounds__(256)
void convert_gram_kernel(const float* __restrict__ X,
                         unsigned short* __restrict__ Xf,
                         unsigned int* __restrict__ counter,
                         float* __restrict__ sColP,             // [NZ][256]
                         float* __restrict__ gPart4)            // [NZ][65536]
{
    __shared__ float red[4][4][64][4];         // 16 KB
    __shared__ float scRed[4][32];
    const int b = blockIdx.x;
    const int t = threadIdx.x;

    // ---- convert slice ----
    {
        int v = b * 256 + t;                   // 131072 fragment-slices of 16B
        if (v == 0) *counter = 0u;
        int tile = v >> 9;
        int kf   = (v >> 6) & 7;
        int lane = v & 63;
        int row  = tile * 16 + (lane & 15);
        int c4   = kf * 8 + (lane >> 4) * 2;   // col/4
        const float4* X4 = reinterpret_cast<const float4*>(X);
        float4 a = X4[row * 64 + c4];
        float4 bb = X4[row * 64 + c4 + 1];
        uint4 o;
        o.x = pack_bf2(a.x, a.y);
        o.y = pack_bf2(a.z, a.w);
        o.z = pack_bf2(bb.x, bb.y);
        o.w = pack_bf2(bb.z, bb.w);
        reinterpret_cast<uint4*>(Xf)[v] = o;
    }
    if (b >= 256) return;                      // blocks 256..511: convert only

    // ---- gram partial ----
    const int lane = t & 63;
    const int w    = t >> 6;
    const int q    = lane >> 4;
    const int n    = lane & 15;
    const int gx   = b & 7, gy = (b >> 3) & 7, gz = b >> 6;   // gz in 0..3
    const int c0   = gx * 32;
    const int d0   = gy * 32;

    f32x4 ac[2][2];
    #pragma unroll
    for (int ct = 0; ct < 2; ++ct)
        #pragma unroll
        for (int dt = 0; dt < 2; ++dt)
            ac[ct][dt] = {0.f, 0.f, 0.f, 0.f};
    float sacc0 = 0.f, sacc1 = 0.f;

    // rows: gz*1024 + w*256 + ks*32 + q*8 + e (bijective over [0,4096))
    const float* base = X + (gz * 1024 + w * 256 + q * 8) * 256;
    for (int ks = 0; ks < 8; ++ks) {
        bf16x8 af[2], bfr[2];
        #pragma unroll
        for (int ct = 0; ct < 2; ++ct) {
            float v[8];
            #pragma unroll
            for (int e = 0; e < 8; ++e) v[e] = base[e * 256 + c0 + ct * 16 + n];
            if (gy == 0) {
                float sv = ((v[0]+v[1])+(v[2]+v[3])) + ((v[4]+v[5])+(v[6]+v[7]));
                if (ct == 0) sacc0 += sv; else sacc1 += sv;
            }
            uint4 u;
            u.x = pack_bf2(v[0], v[1]); u.y = pack_bf2(v[2], v[3]);
            u.z = pack_bf2(v[4], v[5]); u.w = pack_bf2(v[6], v[7]);
            af[ct] = *reinterpret_cast<bf16x8*>(&u);
        }
        #pragma unroll
        for (int dt = 0; dt < 2; ++dt) {
            float v[8];
            #pragma unroll
            for (int e = 0; e < 8; ++e) v[e] = base[e * 256 + d0 + dt * 16 + n];
            uint4 u;
            u.x = pack_bf2(v[0], v[1]); u.y = pack_bf2(v[2], v[3]);
            u.z = pack_bf2(v[4], v[5]); u.w = pack_bf2(v[6], v[7]);
            bfr[dt] = *reinterpret_cast<bf16x8*>(&u);
        }
        #pragma unroll
        for (int ct = 0; ct < 2; ++ct)
            #pragma unroll
            for (int dt = 0; dt < 2; ++dt)
                ac[ct][dt] = __builtin_amdgcn_mfma_f32_16x16x32_bf16(af[ct], bfr[dt], ac[ct][dt], 0, 0, 0);
        base += 32 * 256;
    }

    if (gy == 0) {
        sacc0 += __shfl_xor(sacc0, 16); sacc0 += __shfl_xor(sacc0, 32);
        sacc1 += __shfl_xor(sacc1, 16); sacc1 += __shfl_xor(sacc1, 32);
        if (lane < 16) {
            scRed[w][n]      = sacc0;
            scRed[w][16 + n] = sacc1;
        }
    }

    #pragma unroll
    for (int ct = 0; ct < 2; ++ct)
        #pragma unroll
        for (int dt = 0; dt < 2; ++dt)
            *reinterpret_cast<f32x4*>(&red[w][ct * 2 + dt][lane][0]) = ac[ct][dt];
    __syncthreads();

    if (gy == 0 && t < 32) {
        sColP[gz * 256 + c0 + t] =
            (scRed[0][t] + scRed[1][t]) + (scRed[2][t] + scRed[3][t]);
    }

    const int tile = t >> 6;                   // thread -> (tile, cell)
    const int ln   = t & 63;
    float v[4];
    #pragma unroll
    for (int r = 0; r < 4; ++r)
        v[r] = (red[0][tile][ln][r] + red[1][tile][ln][r])
             + (red[2][tile][ln][r] + red[3][tile][ln][r]);
    const int ct = tile >> 1, dt = tile & 1;
    const int qq = ln >> 4,  nn = ln & 15;
    // Frag dest (R17-verified): f = (gy*2+dt)*8 + gx; slot = (ct*2+(qq>>1))*16+nn;
    // e = (qq&1)*4 + r.
    const int f    = (gy * 2 + dt) * 8 + gx;
    const int slot = (ct * 2 + (qq >> 1)) * 16 + nn;
    const int idx  = (f * 64 + slot) * 8 + (qq & 1) * 4;   // float index, 16B-aligned
    float4 vv = {v[0], v[1], v[2], v[3]};
    *reinterpret_cast<float4*>(&gPart4[gz * 65536 + idx]) = vv;
}

// ---------------- D2: rowstats ------------------------------------------
// Grid 256 x 512 thr: block = one i-tile (16 rows); wave w handles jt=2w,2w+1.
// classSim = mfma(afrag, afrag) diag (wave 0); Y = Xb@(Ghi+Glo) with
// G = sum of NZ z-copies (read fp32, hi/lo-split in regs, R17 RNE arith);
// SQ_i = sum_d Y[i][d]*x[i][d], S_i = sum_d s[d]*x[i][d].
__global__ __launch_bounds__(512)
void rowstats_kernel(const float* __restrict__ X,
                     const unsigned short* __restrict__ Xf,
                     const float* __restrict__ gPart4,
                     const float* __restrict__ sColP,
                     float* __restrict__ c40A, float* __restrict__ threshA,
                     float* __restrict__ posLossA,
                     float* __restrict__ rowPsum, float* __restrict__ rowNsum)
{
    __shared__ float csL[16][8];
    __shared__ float sqL[8][16], smL[8][16];
    const int t    = threadIdx.x;
    const int lane = t & 63;
    const int w    = t >> 6;          // 0..7
    const int q    = lane >> 4;
    const int n    = lane & 15;
    const int it   = blockIdx.x;
    const int i0   = it * 16;

    bf16x8 afrag[8];
    const unsigned short* ap = Xf + (size_t)it * 8 * 512 + lane * 8;
    #pragma unroll
    for (int kf = 0; kf < 8; ++kf)
        afrag[kf] = *reinterpret_cast<const bf16x8*>(ap + kf * 512);

    if (w == 0) {
        f32x4 cac = {0.f, 0.f, 0.f, 0.f};
        #pragma unroll
        for (int kf = 0; kf < 8; ++kf)
            cac = __builtin_amdgcn_mfma_f32_16x16x32_bf16(afrag[kf], afrag[kf], cac, 0, 0, 0);
        #pragma unroll
        for (int r = 0; r < 4; ++r) {
            int row = q * 4 + r;
            if (((row ^ n) >> 3) == 0) csL[row][n & 7] = cac[r];
        }
    }

    float sqa[4] = {0.f, 0.f, 0.f, 0.f};
    float sma[4] = {0.f, 0.f, 0.f, 0.f};
    #pragma unroll
    for (int jj = 0; jj < 2; ++jj) {
        const int jt = w * 2 + jj;
        const float* gp = gPart4 + (size_t)jt * 8 * 512 + lane * 8;
        f32x4 y0 = {0.f, 0.f, 0.f, 0.f};
        f32x4 y1 = {0.f, 0.f, 0.f, 0.f};
        #pragma unroll
        for (int kf = 0; kf < 8; ++kf) {
            float4 ga = *reinterpret_cast<const float4*>(gp + kf * 512);
            float4 gb = *reinterpret_cast<const float4*>(gp + kf * 512 + 4);
            #pragma unroll
            for (int z = 1; z < NZ; ++z) {
                float4 a2 = *reinterpret_cast<const float4*>(gp + z * 65536 + kf * 512);
                float4 b2 = *reinterpret_cast<const float4*>(gp + z * 65536 + kf * 512 + 4);
                ga.x += a2.x; ga.y += a2.y; ga.z += a2.z; ga.w += a2.w;
                gb.x += b2.x; gb.y += b2.y; gb.z += b2.z; gb.w += b2.w;
            }
            uint4 H, L;
            split_pair(ga.x, ga.y, H.x, L.x);
            split_pair(ga.z, ga.w, H.y, L.y);
            split_pair(gb.x, gb.y, H.z, L.z);
            split_pair(gb.z, gb.w, H.w, L.w);
            bf16x8 gh = *reinterpret_cast<bf16x8*>(&H);
            bf16x8 gl = *reinterpret_cast<bf16x8*>(&L);
            y0 = __builtin_amdgcn_mfma_f32_16x16x32_bf16(afrag[kf], gh, y0, 0, 0, 0);
            y1 = __builtin_amdgcn_mfma_f32_16x16x32_bf16(afrag[kf], gl, y1, 0, 0, 0);
        }
        int d = jt * 16 + n;
        float sd = (sColP[d] + sColP[256 + d]) + (sColP[512 + d] + sColP[768 + d]);
        #pragma unroll
        for (int r = 0; r < 4; ++r) {
            float xl = X[(i0 + q * 4 + r) * 256 + d];
            sqa[r] = fmaf(y0[r] + y1[r], xl, sqa[r]);
            sma[r] = fmaf(sd, xl, sma[r]);
        }
    }
    #pragma unroll
    for (int r = 0; r < 4; ++r) {
        float a = sqa[r], b = sma[r];
        #pragma unroll
        for (int m = 8; m >= 1; m >>= 1) {
            a += __shfl_xor(a, m);
            b += __shfl_xor(b, m);
        }
        if (n == 0) { sqL[w][q * 4 + r] = a; smL[w][q * 4 + r] = b; }
    }
    __syncthreads();

    if (t < 16) {
        const int i = i0 + t;
        const int self = i & 7;
        float cs[KCLS];
        #pragma unroll
        for (int m = 0; m < KCLS; ++m) cs[m] = csL[t][m];
        float sii = cs[self];
        float psum = 0.f, psq = 0.f, pmin = 1e30f;
        #pragma unroll
        for (int m = 0; m < KCLS; ++m) {
            if (m != self) {
                psum += cs[m];
                psq  += cs[m] * cs[m];
                pmin  = fminf(pmin, cs[m]);
            }
        }
        const float p = (float)(KCLS - 1);            // 7
        const float mneg = (float)(NROWS - KCLS);     // 4088
        float S  = ((smL[0][t] + smL[1][t]) + (smL[2][t] + smL[3][t]))
                 + ((smL[4][t] + smL[5][t]) + (smL[6][t] + smL[7][t]));
        float SQ = ((sqL[0][t] + sqL[1][t]) + (sqL[2][t] + sqL[3][t]))
                 + ((sqL[4][t] + sqL[5][t]) + (sqL[6][t] + sqL[7][t]));
        float nsum = S - psum - sii;
        float nsq  = SQ - psq - sii * sii;
        float pmean = psum / p;
        float pstd  = sqrtf(fmaxf(psq / p - pmean * pmean, 0.f));
        float nmean = nsum / mneg;
        float nstd  = sqrtf(fmaxf(nsq / mneg - nmean * nmean, 0.f));
        float inter = 0.8f * (nstd * pmean + pstd * nmean) / (pstd + nstd) + 0.1f;
        float pl = 0.f;
        #pragma unroll
        for (int m = 0; m < KCLS; ++m) {
            if (m != self) pl += softplus_poly(-10.f * (cs[m] - inter));
        }
        c40A[i]     = -40.f * inter;
        threshA[i]  = pmin - 0.05f;
        posLossA[i] = pl * (0.2f / p);
        rowPsum[i]  = psum;
        rowNsum[i]  = nsum;
    }
}

// ---------------- D3: loss GEMM (R19-verbatim, R16 loop) ------------------
// Grid (16,32). Block: 4 waves; wave w -> i-tiles [bx*16+w*4, +4) (64 rows,
// A cached in regs). All waves sweep j-tiles [by*8,+8); B staged via LDS
// (global_load_lds, double-buffered). Prologue: 2 loads/row.
__global__ __launch_bounds__(256)
void loss_gemm_kernel(const unsigned short* __restrict__ Xf,
                      const float* __restrict__ c40A,
                      const float* __restrict__ threshA,
                      float* __restrict__ cntPart,
                      float* __restrict__ nlsPart)
{
    __shared__ __align__(16) unsigned short Bs[2][8][512];   // 2 x 8 KB
    __shared__ float c40L[256], threshL[256];

    const int t    = threadIdx.x;
    const int lane = t & 63;
    const int wave = t >> 6;
    const int quad = lane >> 4;
    const int n16  = lane & 15;
    const int it0  = blockIdx.x * 16 + wave * NT;
    const int i0   = it0 * 16;
    const int j0   = blockIdx.y * 128;
    const int jt0  = blockIdx.y * 8;

    bf16x8 afrag[NT][8];
    #pragma unroll
    for (int tt = 0; tt < NT; ++tt) {
        const unsigned short* ap = Xf + ((size_t)(it0 + tt) * 8) * 512 + lane * 8;
        #pragma unroll
        for (int kf = 0; kf < 8; ++kf)
            afrag[tt][kf] = *reinterpret_cast<const bf16x8*>(ap + kf * 512);
    }

    {   // slim prologue: 2 loads/row
        const int i = blockIdx.x * 256 + t;
        c40L[t]    = c40A[i];          // already -40*inter
        threshL[t] = threshA[i];
    }

    auto stage = [&](int buf, int jt) {
        const unsigned short* src =
            Xf + ((size_t)(jt0 + jt) * 8 + wave * 2) * 512 + lane * 8;
        glds16(src,       &Bs[buf][wave * 2][0]);
        glds16(src + 512, &Bs[buf][wave * 2 + 1][0]);
    };

    stage(0, 0);
    __syncthreads();    // drains glds AND publishes c40L/threshL

    float accA[NT][4] = {};       // cnt
    float accB[NT][4] = {};       // nls
    float c40[NT][4], threshR[NT][4];
    int   icls[NT];
    #pragma unroll
    for (int tt = 0; tt < NT; ++tt) {
        icls[tt] = (i0 + tt * 16 + quad * 4) >> 3;
        int lbase = wave * 64 + tt * 16 + quad * 4;
        #pragma unroll
        for (int r = 0; r < 4; ++r) {
            c40[tt][r]     = c40L[lbase + r];
            threshR[tt][r] = threshL[lbase + r];
        }
    }

    int buf = 0;
    #pragma unroll 1
    for (int jt = 0; jt < 8; ++jt) {
        if (jt < 7) stage(buf ^ 1, jt + 1);

        bf16x8 bfr[8];
        #pragma unroll
        for (int kf = 0; kf < 8; ++kf)
            bfr[kf] = *reinterpret_cast<const bf16x8*>(&Bs[buf][kf][lane * 8]);

        f32x4 ac[NT];
        #pragma unroll
        for (int tt = 0; tt < NT; ++tt) ac[tt] = {0.f, 0.f, 0.f, 0.f};
        #pragma unroll
        for (int kf = 0; kf < 8; ++kf) {
            #pragma unroll
            for (int tt = 0; tt < NT; ++tt)
                ac[tt] = __builtin_amdgcn_mfma_f32_16x16x32_bf16(afrag[tt][kf], bfr[kf], ac[tt], 0, 0, 0);
        }

        const int jcls = (j0 + jt * 16 + n16) >> 3;
        #pragma unroll
        for (int tt = 0; tt < NT; ++tt) {
            const bool neg = (icls[tt] != jcls);
            #pragma unroll
            for (int r = 0; r < 4; ++r) {
                float s  = ac[tt][r];
                float sp = softplus_poly(fmaf(40.f, s, c40[tt][r]));
                float m  = (neg && s > threshR[tt][r]) ? 1.f : 0.f;
                accA[tt][r] += m;
                accB[tt][r] = fmaf(m, sp, accB[tt][r]);
            }
        }

        __syncthreads();
        buf ^= 1;
    }

    // quad shuffle-reduce -> float4 partial stores
    #pragma unroll
    for (int tt = 0; tt < NT; ++tt) {
        #pragma unroll
        for (int r = 0; r < 4; ++r) {
            #pragma unroll
            for (int m = 8; m >= 1; m >>= 1) {
                accA[tt][r] += __shfl_xor(accA[tt][r], m);
                accB[tt][r] += __shfl_xor(accB[tt][r], m);
            }
        }
        if (n16 == 0) {
            int base = blockIdx.y * NROWS + i0 + tt * 16 + quad * 4;
            float4 va = {accA[tt][0], accA[tt][1], accA[tt][2], accA[tt][3]};
            float4 vb = {accB[tt][0], accB[tt][1], accB[tt][2], accB[tt][3]};
            *reinterpret_cast<float4*>(&cntPart[base]) = va;
            *reinterpret_cast<float4*>(&nlsPart[base]) = vb;
        }
    }
}

// ---------------- D4: finalAB (R16-verbatim) ------------------------------
__global__ __launch_bounds__(256)
void finalAB_kernel(const float* __restrict__ cntPart,
                    const float* __restrict__ nlsPart,
                    const float* __restrict__ posLossA,
                    const float* __restrict__ rowPsum,
                    const float* __restrict__ rowNsum,
                    float* __restrict__ blkPart,      // 16*4 floats
                    unsigned int* __restrict__ counter,
                    float* __restrict__ out)
{
    const int t = threadIdx.x;
    const int i = blockIdx.x * 256 + t;

    float c = 0.f, n = 0.f;
    #pragma unroll
    for (int b = 0; b < NJB; ++b) {
        c += cntPart[b * NROWS + i];
        n += nlsPart[b * NROWS + i];
    }
    float loss = (c > 0.f) ? (posLossA[i] + 0.05f * n / c) : 0.f;
    float inv  = (c > 0.f) ? 0.f : 1.f;
    float pd   = rowPsum[i];
    float nd   = rowNsum[i];

    #pragma unroll
    for (int off = 32; off > 0; off >>= 1) {
        loss += __shfl_down(loss, off);
        inv  += __shfl_down(inv, off);
        pd   += __shfl_down(pd, off);
        nd   += __shfl_down(nd, off);
    }
    __shared__ float sl[4], si[4], sp[4], sq[4];
    int w = t >> 6;
    if ((t & 63) == 0) { sl[w] = loss; si[w] = inv; sp[w] = pd; sq[w] = nd; }
    __syncthreads();
    if (t == 0) {
        blkPart[blockIdx.x * 4 + 0] = sl[0] + sl[1] + sl[2] + sl[3];
        blkPart[blockIdx.x * 4 + 1] = si[0] + si[1] + si[2] + si[3];
        blkPart[blockIdx.x * 4 + 2] = sp[0] + sp[1] + sp[2] + sp[3];
        blkPart[blockIdx.x * 4 + 3] = sq[0] + sq[1] + sq[2] + sq[3];
        __threadfence();
        unsigned int old = atomicAdd(counter, 1u);
        sl[0] = (old == 15u) ? 1.f : 0.f;       // reuse LDS as flag
    }
    __syncthreads();
    if (sl[0] != 0.f && t < 64) {
        // last block: coherent read of all 64 partials (distinct addresses)
        float v = atomicAdd(&blkPart[t], 0.f);
        #pragma unroll
        for (int off = 4; off < 64; off <<= 1) v += __shfl_xor(v, off);
        // lanes 0..3 now hold totals: loss, inv, psum, nsum
        if (t == 0) out[0] = v / (float)NROWS;
        if (t == 1) out[1] = v / (float)NROWS;
        if (t == 2) out[2] = v / ((float)NROWS * (float)(KCLS - 1));
        if (t == 3) out[3] = v / ((float)NROWS * (float)(NROWS - KCLS));
    }
}

extern "C" void kernel_launch(void* const* d_in, const int* in_sizes, int n_in,
                              void* d_out, int out_size, void* d_ws, size_t ws_size,
                              hipStream_t stream)
{
    const float* X = (const float*)d_in[0];

    float* ws       = (float*)d_ws;
    float* cntPart  = ws;                                   // 32*4096
    float* nlsPart  = cntPart + NJB * NROWS;                // 32*4096
    float* sColP    = nlsPart + NJB * NROWS;                // 4*256
    float* c40A     = sColP + NZ * 256;                     // 4096
    float* threshA  = c40A + NROWS;                         // 4096
    float* posLossA = threshA + NROWS;                      // 4096
    float* rowPsum  = posLossA + NROWS;                     // 4096
    float* rowNsum  = rowPsum + NROWS;                      // 4096
    float* blkPart  = rowNsum + NROWS;                      // 64
    unsigned int* counter = (unsigned int*)(blkPart + 64);  // 1 (+pad)
    float* gPart4   = (float*)(counter + 32);               // 4*65536 (1 MB)
    unsigned short* Xf = (unsigned short*)(gPart4 + NZ * 65536);  // 2 MB
    // total ws use: ~4.2 MB; counter zeroed by D1

    convert_gram_kernel<<<512, 256, 0, stream>>>(X, Xf, counter, sColP, gPart4);

    rowstats_kernel<<<256, 512, 0, stream>>>(X, Xf, gPart4, sColP,
                                             c40A, threshA, posLossA,
                                             rowPsum, rowNsum);

    loss_gemm_kernel<<<dim3(16, 32), 256, 0, stream>>>(Xf, c40A, threshA,
                                                       cntPart, nlsPart);

    finalAB_kernel<<<16, 256, 0, stream>>>(cntPart, nlsPart, posLossA,
                                           rowPsum, rowNsum, blkPart, counter,
                                           (float*)d_out);
}

// Round 9
// 96.816 us; speedup vs baseline: 1.1277x; 1.1277x over previous
//
#include <hip/hip_runtime.h>
#include <math.h>

// MarginDevianceLoss: N=4096, D=256, K=8, targets = i/8.
// Outputs: [loss, prec, pos_d, neg_d] fp32.
//
// R23 = R16 verbatim (champion restore). Session ledger: every structural
// deviation regressed or nulled —
//   Gram factorization (R17/R18/R19/R22): +10..+42us, 3x falsified;
//   occupancy 2x/4x (R18/R19): null;
//   dual-tile barrier epochs (R21): +3us;
//   finalAB-into-GEMM fusion (R20): VGPR capped 128 -> A-frag spill, +47us.
// Structure: convert -> statsGemm -> lossGemm(+stats prologue) -> finalAB.
// R16 = R15 with the GEMM wave i-footprint widened 2 -> 4 i-tiles (64 rows/
// wave, 256 rows/block, grid 16x32): per staged B j-tile a wave issues
// 64 MFMA vs 8 ds_read_b128 -> MFMA-dominant. A-frags cost 128 VGPRs
// (~200 total, 2 waves/SIMD).
// Kept lessons: frag-major bf16 Xf + glds B-staging (R11); no inline fp32
// staging (R12); no big atomic fan-in / grid barriers (R7/R13); no reduction
// tails inside register-critical MFMA kernels (R20).

#define NROWS 4096
#define DIM   256
#define KCLS  8
#define NJB   32     // j-blocks = partials per row
#define NT    4      // i-tiles per wave

typedef __bf16 bf16x8 __attribute__((ext_vector_type(8)));
typedef float  f32x4  __attribute__((ext_vector_type(4)));

// log(1+exp(z)) = max(z,0) + ln2 * log2(1 + exp2(-|z|*log2e));
// log2(1+u), u in (0,1], quartic fit (abs err <= ~4e-4).
__device__ __forceinline__ float softplus_poly(float z) {
    float u = __builtin_exp2f(-1.4426950408889634f * __builtin_fabsf(z));
    float p = u * (1.4426950f + u * (-0.6949650f + u * (0.3454302f + u * -0.0931600f)));
    return fmaf(p, 0.6931471805599453f, fmaxf(z, 0.f));
}

__device__ __forceinline__ unsigned int pack_bf2(float a, float b) {
    unsigned int ua = __float_as_uint(a);
    unsigned int ub = __float_as_uint(b);
    ua = (ua + 0x7FFFu + ((ua >> 16) & 1u)) >> 16;   // RNE
    ub = (ub + 0x7FFFu + ((ub >> 16) & 1u)) >> 16;
    return ua | (ub << 16);
}

__device__ __forceinline__ void glds16(const unsigned short* g, unsigned short* l) {
    // HW: each lane reads 16 B at its own g; LDS dest = uniform l + lane*16.
    __builtin_amdgcn_global_load_lds(
        (const __attribute__((address_space(1))) void*)g,
        (__attribute__((address_space(3))) void*)l, 16, 0, 0);
}

// X (fp32 row-major) -> Xf (bf16 fragment-major):
// Xf[((tile*8 + kf)*64 + lane)*8 + e] = X[tile*16 + (lane&15)][kf*32 + (lane>>4)*8 + e]
// Also zeroes the finalAB done-counter (used 2 dispatches later).
__global__ __launch_bounds__(256)
void convert_kernel(const float* __restrict__ X, unsigned short* __restrict__ Xf,
                    unsigned int* __restrict__ counter)
{
    int v = blockIdx.x * 256 + threadIdx.x;    // 131072 fragment-slices of 16 B
    if (v == 0) *counter = 0u;
    int tile = v >> 9;
    int kf   = (v >> 6) & 7;
    int lane = v & 63;
    int row  = tile * 16 + (lane & 15);
    int c4   = kf * 8 + (lane >> 4) * 2;       // col/4
    const float4* X4 = reinterpret_cast<const float4*>(X);
    float4 a = X4[row * 64 + c4];
    float4 b = X4[row * 64 + c4 + 1];
    uint4 o;
    o.x = pack_bf2(a.x, a.y);
    o.y = pack_bf2(a.z, a.w);
    o.z = pack_bf2(b.x, b.y);
    o.w = pack_bf2(b.z, b.w);
    reinterpret_cast<uint4*>(Xf)[v] = o;
}

// Grid (16,32). Block: 4 waves; wave w -> i-tiles [bx*16+w*4, +4) (64 rows,
// A cached in regs for K=256 = 128 VGPRs). All waves sweep j-tiles [by*8,+8);
// B staged via LDS (global_load_lds, double-buffered, 2 frags/wave/tile).
// PASS 1 (STATS=1): sum/sumsq epilogue + diag classSim -> float4 partials.
// PASS 2 (STATS=0): prologue computes per-row inter/thresh from pass-1
//   partials (256 rows/block, 1/thread; by==0 writes posLoss/psum/nsum),
//   then branchless filter + poly-softplus -> cnt/nls partials.
template<int STATS>
__global__ __launch_bounds__(256)
void gemm_pass_kernel(const unsigned short* __restrict__ Xf,
                      const float* __restrict__ sumPart,   // in  (pass 2)
                      const float* __restrict__ sqPart,    // in  (pass 2)
                      float* __restrict__ classSim,        // out p1 / in p2
                      float* __restrict__ outPartA,        // sumPart / cntPart
                      float* __restrict__ outPartB,        // sqPart  / nlsPart
                      float* __restrict__ posLossA,
                      float* __restrict__ rowPsum,
                      float* __restrict__ rowNsum)
{
    __shared__ __align__(16) unsigned short Bs[2][8][512];   // 2 x 8 KB
    __shared__ float interL[256], threshL[256];

    const int t    = threadIdx.x;
    const int lane = t & 63;
    const int wave = t >> 6;
    const int quad = lane >> 4;
    const int n16  = lane & 15;
    const int it0  = blockIdx.x * 16 + wave * NT;
    const int i0   = it0 * 16;
    const int j0   = blockIdx.y * 128;
    const int jt0  = blockIdx.y * 8;
    // block rows [bx*256,+256) x cols [by*128,+128): same-class pairs exist
    // iff by>>1 == bx.
    const bool diag = ((blockIdx.y >> 1) == blockIdx.x);

    // A fragments: NT i-tiles x 8 k-frags, coalesced 1-KB global loads
    bf16x8 afrag[NT][8];
    #pragma unroll
    for (int tt = 0; tt < NT; ++tt) {
        const unsigned short* ap = Xf + ((size_t)(it0 + tt) * 8) * 512 + lane * 8;
        #pragma unroll
        for (int kf = 0; kf < 8; ++kf)
            afrag[tt][kf] = *reinterpret_cast<const bf16x8*>(ap + kf * 512);
    }

    // ---- pass-2 prologue: stats for this block's 256 i-rows (1/thread) ----
    if constexpr (!STATS) {
        const int i = blockIdx.x * 256 + t;
        const int self = i & 7;
        float S = 0.f, SQ = 0.f;
        #pragma unroll
        for (int b = 0; b < NJB; ++b) {
            S  += sumPart[b * NROWS + i];
            SQ += sqPart[b * NROWS + i];
        }
        float4 c0 = reinterpret_cast<const float4*>(classSim)[i * 2];
        float4 c1 = reinterpret_cast<const float4*>(classSim)[i * 2 + 1];
        float cs[KCLS] = {c0.x, c0.y, c0.z, c0.w, c1.x, c1.y, c1.z, c1.w};
        float sii = cs[self];
        float psum = 0.f, psq = 0.f, pmin = 1e30f;
        #pragma unroll
        for (int m = 0; m < KCLS; ++m) {
            if (m != self) {
                psum += cs[m];
                psq  += cs[m] * cs[m];
                pmin  = fminf(pmin, cs[m]);
            }
        }
        const float p = (float)(KCLS - 1);            // 7
        const float mneg = (float)(NROWS - KCLS);     // 4088
        float nsum = S - psum - sii;
        float nsq  = SQ - psq - sii * sii;
        float pmean = psum / p;
        float pstd  = sqrtf(fmaxf(psq / p - pmean * pmean, 0.f));
        float nmean = nsum / mneg;
        float nstd  = sqrtf(fmaxf(nsq / mneg - nmean * nmean, 0.f));
        float inter = 0.8f * (nstd * pmean + pstd * nmean) / (pstd + nstd) + 0.1f;
        interL[t]  = inter;
        threshL[t] = pmin - 0.05f;
        if (blockIdx.y == 0) {                  // single-writer outputs
            float pl = 0.f;
            #pragma unroll
            for (int m = 0; m < KCLS; ++m) {
                if (m != self) pl += softplus_poly(-10.f * (cs[m] - inter));
            }
            posLossA[i] = pl * (0.2f / p);
            rowPsum[i]  = psum;
            rowNsum[i]  = nsum;
        }
    }

    // stage B frags for j-tile jt into buffer buf: wave w loads frags 2w,2w+1
    auto stage = [&](int buf, int jt) {
        const unsigned short* src =
            Xf + ((size_t)(jt0 + jt) * 8 + wave * 2) * 512 + lane * 8;
        glds16(src,       &Bs[buf][wave * 2][0]);
        glds16(src + 512, &Bs[buf][wave * 2 + 1][0]);
    };

    stage(0, 0);
    __syncthreads();    // drains glds AND publishes interL/threshL

    float accA[NT][4] = {};       // sI / cnt
    float accB[NT][4] = {};       // sqI / nls
    float c40[NT][4], threshR[NT][4];
    int   icls[NT];
    if constexpr (!STATS) {
        #pragma unroll
        for (int tt = 0; tt < NT; ++tt) {
            icls[tt] = (i0 + tt * 16 + quad * 4) >> 3;
            int lbase = wave * 64 + tt * 16 + quad * 4;   // local row in block
            #pragma unroll
            for (int r = 0; r < 4; ++r) {
                c40[tt][r]     = -40.f * interL[lbase + r];
                threshR[tt][r] = threshL[lbase + r];
            }
        }
    }

    int buf = 0;
    #pragma unroll 1
    for (int jt = 0; jt < 8; ++jt) {
        if (jt < 7) stage(buf ^ 1, jt + 1);

        bf16x8 bfr[8];
        #pragma unroll
        for (int kf = 0; kf < 8; ++kf)
            bfr[kf] = *reinterpret_cast<const bf16x8*>(&Bs[buf][kf][lane * 8]);

        f32x4 ac[NT];
        #pragma unroll
        for (int tt = 0; tt < NT; ++tt) ac[tt] = {0.f, 0.f, 0.f, 0.f};
        #pragma unroll
        for (int kf = 0; kf < 8; ++kf) {
            #pragma unroll
            for (int tt = 0; tt < NT; ++tt)
                ac[tt] = __builtin_amdgcn_mfma_f32_16x16x32_bf16(afrag[tt][kf], bfr[kf], ac[tt], 0, 0, 0);
        }

        if constexpr (STATS) {
            #pragma unroll
            for (int tt = 0; tt < NT; ++tt)
                #pragma unroll
                for (int r = 0; r < 4; ++r) {
                    float s = ac[tt][r];
                    accA[tt][r] += s;
                    accB[tt][r] = fmaf(s, s, accB[tt][r]);
                }
            if (diag) {                    // wave-uniform: 32/512 blocks
                int j = j0 + jt * 16 + n16;
                #pragma unroll
                for (int tt = 0; tt < NT; ++tt)
                    #pragma unroll
                    for (int r = 0; r < 4; ++r) {
                        int i = i0 + tt * 16 + quad * 4 + r;
                        if (((i ^ j) >> 3) == 0)
                            classSim[i * KCLS + (j & 7)] = ac[tt][r];
                    }
            }
        } else {
            const int jcls = (j0 + jt * 16 + n16) >> 3;
            #pragma unroll
            for (int tt = 0; tt < NT; ++tt) {
                const bool neg = (icls[tt] != jcls);
                #pragma unroll
                for (int r = 0; r < 4; ++r) {
                    float s  = ac[tt][r];
                    float sp = softplus_poly(fmaf(40.f, s, c40[tt][r]));
                    float m  = (neg && s > threshR[tt][r]) ? 1.f : 0.f;
                    accA[tt][r] += m;
                    accB[tt][r] = fmaf(m, sp, accB[tt][r]);
                }
            }
        }

        __syncthreads();    // drains glds for jt+1; frees buf for jt+2
        buf ^= 1;
    }

    // quad shuffle-reduce (16 lanes share rows) -> float4 partial stores
    #pragma unroll
    for (int tt = 0; tt < NT; ++tt) {
        #pragma unroll
        for (int r = 0; r < 4; ++r) {
            #pragma unroll
            for (int m = 8; m >= 1; m >>= 1) {
                accA[tt][r] += __shfl_xor(accA[tt][r], m);
                accB[tt][r] += __shfl_xor(accB[tt][r], m);
            }
        }
        if (n16 == 0) {
            int base = blockIdx.y * NROWS + i0 + tt * 16 + quad * 4;
            float4 va = {accA[tt][0], accA[tt][1], accA[tt][2], accA[tt][3]};
            float4 vb = {accB[tt][0], accB[tt][1], accB[tt][2], accB[tt][3]};
            *reinterpret_cast<float4*>(&outPartA[base]) = va;
            *reinterpret_cast<float4*>(&outPartB[base]) = vb;
        }
    }
}

// 16 blocks x 256 threads; thread -> one row. Reduce cnt/nls partials ->
// rowLoss/rowInv, block-reduce 4 sums, last block combines -> out.
__global__ __launch_bounds__(256)
void finalAB_kernel(const float* __restrict__ cntPart,
                    const float* __restrict__ nlsPart,
                    const float* __restrict__ posLossA,
                    const float* __restrict__ rowPsum,
                    const float* __restrict__ rowNsum,
                    float* __restrict__ blkPart,      // 16*4 floats
                    unsigned int* __restrict__ counter,
                    float* __restrict__ out)
{
    const int t = threadIdx.x;
    const int i = blockIdx.x * 256 + t;

    float c = 0.f, n = 0.f;
    #pragma unroll
    for (int b = 0; b < NJB; ++b) {
        c += cntPart[b * NROWS + i];
        n += nlsPart[b * NROWS + i];
    }
    float loss = (c > 0.f) ? (posLossA[i] + 0.05f * n / c) : 0.f;
    float inv  = (c > 0.f) ? 0.f : 1.f;
    float pd   = rowPsum[i];
    float nd   = rowNsum[i];

    #pragma unroll
    for (int off = 32; off > 0; off >>= 1) {
        loss += __shfl_down(loss, off);
        inv  += __shfl_down(inv, off);
        pd   += __shfl_down(pd, off);
        nd   += __shfl_down(nd, off);
    }
    __shared__ float sl[4], si[4], sp[4], sq[4];
    int w = t >> 6;
    if ((t & 63) == 0) { sl[w] = loss; si[w] = inv; sp[w] = pd; sq[w] = nd; }
    __syncthreads();
    if (t == 0) {
        blkPart[blockIdx.x * 4 + 0] = sl[0] + sl[1] + sl[2] + sl[3];
        blkPart[blockIdx.x * 4 + 1] = si[0] + si[1] + si[2] + si[3];
        blkPart[blockIdx.x * 4 + 2] = sp[0] + sp[1] + sp[2] + sp[3];
        blkPart[blockIdx.x * 4 + 3] = sq[0] + sq[1] + sq[2] + sq[3];
        __threadfence();
        unsigned int old = atomicAdd(counter, 1u);
        sl[0] = (old == 15u) ? 1.f : 0.f;       // reuse LDS as flag
    }
    __syncthreads();
    if (sl[0] != 0.f && t < 64) {
        // last block: coherent read of all 64 partials (distinct addresses)
        float v = atomicAdd(&blkPart[t], 0.f);
        #pragma unroll
        for (int off = 4; off < 64; off <<= 1) v += __shfl_xor(v, off);
        // lanes 0..3 now hold totals: loss, inv, psum, nsum
        if (t == 0) out[0] = v / (float)NROWS;
        if (t == 1) out[1] = v / (float)NROWS;
        if (t == 2) out[2] = v / ((float)NROWS * (float)(KCLS - 1));
        if (t == 3) out[3] = v / ((float)NROWS * (float)(NROWS - KCLS));
    }
}

extern "C" void kernel_launch(void* const* d_in, const int* in_sizes, int n_in,
                              void* d_out, int out_size, void* d_ws, size_t ws_size,
                              hipStream_t stream)
{
    const float* X = (const float*)d_in[0];

    float* ws       = (float*)d_ws;
    float* sumPart  = ws;                                   // 32*4096
    float* sqPart   = sumPart + NJB * NROWS;                // 32*4096
    float* cntPart  = sqPart  + NJB * NROWS;                // 32*4096
    float* nlsPart  = cntPart + NJB * NROWS;                // 32*4096
    float* classSim = nlsPart + NJB * NROWS;                // 4096*8
    float* posLossA = classSim + NROWS * KCLS;              // 4096
    float* rowPsum  = posLossA + NROWS;
    float* rowNsum  = rowPsum + NROWS;
    float* blkPart  = rowNsum + NROWS;                      // 64
    unsigned int* counter = (unsigned int*)(blkPart + 64);  // 1
    unsigned short* Xf = (unsigned short*)(counter + 16);   // 2 MB
    // total ws use: ~2.4 MB; counter zeroed by convert (2 dispatches early)

    convert_kernel<<<512, 256, 0, stream>>>(X, Xf, counter);

    dim3 grid(16, 32);
    gemm_pass_kernel<1><<<grid, 256, 0, stream>>>(Xf, nullptr, nullptr,
                                                  classSim, sumPart, sqPart,
                                                  nullptr, nullptr, nullptr);

    gemm_pass_kernel<0><<<grid, 256, 0, stream>>>(Xf, sumPart, sqPart,
                                                  classSim, cntPart, nlsPart,
                                                  posLossA, rowPsum, rowNsum);

    finalAB_kernel<<<16, 256, 0, stream>>>(cntPart, nlsPart, posLossA,
                                           rowPsum, rowNsum, blkPart, counter,
                                           (float*)d_out);
}